// Round 9
// baseline (692.872 us; speedup 1.0000x reference)
//
#include <hip/hip_runtime.h>

#define T_LEN 2048
#define B_SZ  64
#define I_DIM 128
#define H_DIM 256

typedef _Float16 f16;
typedef _Float16 f16x8 __attribute__((ext_vector_type(8)));
typedef float    f32x4 __attribute__((ext_vector_type(4)));
typedef int      i32x4 __attribute__((ext_vector_type(4)));

__device__ __forceinline__ float fast_sigmoid(float z) {
  return __builtin_amdgcn_rcpf(1.0f + __expf(-z));
}

// Raw barrier: orders LDS (lgkmcnt(0)) but leaves global prefetch loads in
// flight across the barrier (no vmcnt drain, unlike __syncthreads).
#define WG_BARRIER() do {                                  \
  asm volatile("s_waitcnt lgkmcnt(0)" ::: "memory");       \
  __builtin_amdgcn_s_barrier();                            \
  asm volatile("" ::: "memory");                           \
  __builtin_amdgcn_sched_barrier(0);                       \
} while (0)

// ---------------------------------------------------------------------------
// Kernel 1: xproj[t][b][:] = x[b][t][:] @ Wx + bias   (written into d_out)
// grid (16, 64): blockIdx.x = 128-t chunk, blockIdx.y = b. 256 thr = 4 waves.
// Wave w owns cols [64w, 64w+64).   (f16 MFMA is right here: M=16 tile full)
// ---------------------------------------------------------------------------
__global__ __launch_bounds__(256) void xproj_kernel(
    const float* __restrict__ x, const float* __restrict__ W,
    const float* __restrict__ bias, float* __restrict__ out) {
  const int b    = blockIdx.y;
  const int tc   = blockIdx.x * 128;
  const int w    = threadIdx.x >> 6;
  const int lane = threadIdx.x & 63;
  const int cl   = lane & 15;
  const int kh   = lane >> 4;

  // Wx fragments: B[k][c], c = 64w+16g+cl, k = 32q+8kh+j (8 consecutive k/lane)
  f16x8 Bf[4][4];
#pragma unroll
  for (int g = 0; g < 4; ++g) {
    const int c = 64 * w + 16 * g + cl;
#pragma unroll
    for (int q = 0; q < 4; ++q)
#pragma unroll
      for (int j = 0; j < 8; ++j)
        Bf[g][q][j] = (f16)W[(32 * q + 8 * kh + j) * H_DIM + c];
  }
  float bv[4];
#pragma unroll
  for (int g = 0; g < 4; ++g) bv[g] = bias[64 * w + 16 * g + cl];

#pragma unroll 1
  for (int tb = 0; tb < 128; tb += 16) {
    const int t0 = tc + tb;
    // A fragments: A[r][k] = x[b][t0+r][k], r = cl, k = 8kh+j+32q
    const float* xrow = x + ((size_t)b * T_LEN + (t0 + cl)) * I_DIM + 8 * kh;
    f16x8 Af[4];
#pragma unroll
    for (int q = 0; q < 4; ++q) {
      float4 u0 = *(const float4*)(xrow + 32 * q);
      float4 u1 = *(const float4*)(xrow + 32 * q + 4);
      f16x8 a;
      a[0] = (f16)u0.x; a[1] = (f16)u0.y; a[2] = (f16)u0.z; a[3] = (f16)u0.w;
      a[4] = (f16)u1.x; a[5] = (f16)u1.y; a[6] = (f16)u1.z; a[7] = (f16)u1.w;
      Af[q] = a;
    }
#pragma unroll
    for (int g = 0; g < 4; ++g) {
      f32x4 acc = {0.f, 0.f, 0.f, 0.f};
#pragma unroll
      for (int q = 0; q < 4; ++q)
        acc = __builtin_amdgcn_mfma_f32_16x16x32_f16(Af[q], Bf[g][q], acc, 0, 0, 0);
      // D: row = 4kh+j, col = cl (+16g+64w)
#pragma unroll
      for (int j = 0; j < 4; ++j) {
        const int t = t0 + 4 * kh + j;
        out[((size_t)t * B_SZ + b) * H_DIM + 64 * w + 16 * g + cl] = acc[j] + bv[g];
      }
    }
  }
}

// ---------------------------------------------------------------------------
// Kernel 2: sequential scan — i8 MFMA, 8 waves (2 per SIMD) for tail overlap.
//
// r8 post-mortem: the ~436-cyc non-pipe tail is per-wave SERIAL work (MFMA
// chain drain, sigmoid->quant->ds_write chain, barrier) that a single wave
// per SIMD cannot hide; read-latency overlap tricks were null. Fix: TWO
// waves per SIMD (512 thr), each owning 32 cols (2 tiles). MFMA pipe demand
// per SIMD is unchanged (2 x 8 = 16 MFMA = 326 cyc) but the two waves'
// serial tails interleave on the SIMD, hiding most of the non-pipe time.
// Per-wave chains: 4 accumulators x 2-deep (never latency-bound), 1 cndmask
// z-selection. LDS read traffic stays tiny in i8 (32 x 16B guarded reads/CU).
//
// Fixed-point encoding (absmax floor-equal to f16, verified r7):
//   hq = round(h*254) - 127 ; wq = round(Wh*2490)
//   z  = idot/(254*2490) + zoff + xp,  zoff = 127*colsum/(254*2490)
// ---------------------------------------------------------------------------
#define MFMAI8(A, B, C) __builtin_amdgcn_mfma_i32_16x16x64_i8((A), (B), (C), 0, 0, 0)

#define SW_SCALE 2490.0f
#define INVS (1.0f / (254.0f * SW_SCALE))
#define RS (B_SZ * H_DIM)

#define RNN_STEP(pp, RB) do {                                                \
  if (rdlane) {                                                              \
    Aq0 = *(const i32x4*)&hbuf8[RB][rd0];                                    \
    Aq1 = *(const i32x4*)&hbuf8[RB][rd1];                                    \
    Aq2 = *(const i32x4*)&hbuf8[RB][rd2];                                    \
    Aq3 = *(const i32x4*)&hbuf8[RB][rd3];                                    \
  }                                                                          \
  i32x4 a0L = MFMAI8(Aq0, Bq[0][0], Zacc);                                   \
  i32x4 a1L = MFMAI8(Aq0, Bq[1][0], Zacc);                                   \
  i32x4 a0H = MFMAI8(Aq2, Bq[0][2], Zacc);                                   \
  i32x4 a1H = MFMAI8(Aq2, Bq[1][2], Zacc);                                   \
  a0L = MFMAI8(Aq1, Bq[0][1], a0L);                                          \
  a1L = MFMAI8(Aq1, Bq[1][1], a1L);                                          \
  a0H = MFMAI8(Aq3, Bq[0][3], a0H);                                          \
  a1H = MFMAI8(Aq3, Bq[1][3], a1H);                                          \
  int i0 = a0L[0] + a0H[0];                                                  \
  int i1 = a1L[0] + a1H[0];                                                  \
  int idot = g1 ? i1 : i0;                                                   \
  float hh = fast_sigmoid(__builtin_fmaf((float)idot, INVS, zoff + (pp)));   \
  int hq = (int)__builtin_rintf(__builtin_fmaf(hh, 254.0f, -127.0f));        \
  if (act) hbuf8[(RB) ^ 1][colx] = (signed char)hq;                          \
  WG_BARRIER();                                                              \
  if (act) *opSt = hh;                                                       \
  opSt += RS;                                                                \
} while (0)

__global__ __launch_bounds__(512, 2) void rnn_kernel(
    const float* __restrict__ W, float* out) {
  const int b    = blockIdx.x;
  const int tid  = threadIdx.x;
  const int w    = tid >> 6;          // wave 0..7, owns cols [32w, 32w+32)
  const int lane = tid & 63;
  const int cl   = lane & 15;
  const int kh   = lane >> 4;

  __shared__ __align__(16) signed char hbuf8[2][H_DIM];

  const bool act  = (lane < 32);
  const int  colx = 32 * w + (lane & 31);   // this lane's output column

  // h0 = 0  ->  hq = round(0*254) - 127 = -127
  if (act) {
    hbuf8[0][colx] = (signed char)-127;
    hbuf8[1][colx] = (signed char)-127;
  }

  // Quantized Wh fragments: tile g (g=0,1), K-chunk q: c = 32w+16g+cl,
  // k = 64q + 16kh + 4d + j. 2 tiles x 4 q x 4 VGPR = 32 VGPRs.
  i32x4 Bq[2][4];
#pragma unroll
  for (int g = 0; g < 2; ++g) {
    const int c = 32 * w + 16 * g + cl;
#pragma unroll
    for (int q = 0; q < 4; ++q) {
#pragma unroll
      for (int d = 0; d < 4; ++d) {
        int dw = 0;
#pragma unroll
        for (int j = 0; j < 4; ++j) {
          const int k = 64 * q + 16 * kh + 4 * d + j;
          const int qv = (int)__builtin_rintf(W[(I_DIM + k) * H_DIM + c] * SW_SCALE);
          dw |= (qv & 0xff) << (8 * j);
        }
        Bq[g][q][d] = dw;
      }
    }
  }

  // Per-thread column constant: zoff = 127 * colsum(colx) * INVS.
  int cs = 0;
#pragma unroll 4
  for (int k = 0; k < H_DIM; ++k)
    cs += (int)__builtin_rintf(W[(I_DIM + k) * H_DIM + colx] * SW_SCALE);
  const float zoff = 127.0f * (float)cs * INVS;

  // A fragments: rows {0,4} of the shared A-tile carry hq (reader lanes
  // cl in {0,4}, i.e. (cl & 11) == 0); all other rows stay zero forever.
  i32x4 Aq0 = {0, 0, 0, 0}, Aq1 = {0, 0, 0, 0};
  i32x4 Aq2 = {0, 0, 0, 0}, Aq3 = {0, 0, 0, 0};
  const i32x4 Zacc = {0, 0, 0, 0};

  const bool rdlane = ((cl & 11) == 0);
  const int  rd0 = 0   + 16 * kh;
  const int  rd1 = 64  + 16 * kh;
  const int  rd2 = 128 + 16 * kh;
  const int  rd3 = 192 + 16 * kh;

  // z-selection: lanes 0-15 take tile 0 (D-row 0), lanes 16-31 tile 1
  // (D-row 4); lanes 32-63 duplicate harmlessly.
  const bool g1 = ((lane >> 4) & 1) != 0;

  const size_t rowstride = RS;
  float* op   = out + (size_t)b * H_DIM + colx;  // &out[(t*B+b)*H+colx], t=0
  float* opSt = op;
  const float* opPre = op + 4 * rowstride;

  __syncthreads();

  // xp prefetch pipeline, depth 4 (coalesced; upper half-lanes duplicate)
  float p0 = op[0 * rowstride];
  float p1 = op[1 * rowstride];
  float p2 = op[2 * rowstride];
  float p3 = op[3 * rowstride];

  // main loop: t = 0..2043 (511 x 4 steps), prefetch rows t+4..t+7
#pragma unroll 1
  for (int it = 0; it < (T_LEN - 4) / 4; ++it) {
    float n0 = opPre[0 * rowstride];
    RNN_STEP(p0, 0); p0 = n0;
    float n1 = opPre[1 * rowstride];
    RNN_STEP(p1, 1); p1 = n1;
    float n2 = opPre[2 * rowstride];
    RNN_STEP(p2, 0); p2 = n2;
    float n3 = opPre[3 * rowstride];
    RNN_STEP(p3, 1); p3 = n3;
    opPre += 4 * rowstride;
  }
  // epilogue: t = 2044..2047, no prefetch
  RNN_STEP(p0, 0);
  RNN_STEP(p1, 1);
  RNN_STEP(p2, 0);
  RNN_STEP(p3, 1);
}

extern "C" void kernel_launch(void* const* d_in, const int* in_sizes, int n_in,
                              void* d_out, int out_size, void* d_ws, size_t ws_size,
                              hipStream_t stream) {
  (void)in_sizes; (void)n_in; (void)d_ws; (void)ws_size; (void)out_size;
  const float* x    = (const float*)d_in[0];
  const float* W    = (const float*)d_in[1];
  const float* bias = (const float*)d_in[2];
  float* out = (float*)d_out;

  xproj_kernel<<<dim3(16, 64), 256, 0, stream>>>(x, W, bias, out);
  rnn_kernel<<<64, 512, 0, stream>>>(W, out);
}